// Round 2
// baseline (10120.530 us; speedup 1.0000x reference)
//
#include <hip/hip_runtime.h>
#include <hip/hip_bf16.h>

typedef __hip_bfloat16 bf16;
#define DEVI __device__ __forceinline__

DEVI float bf2f(bf16 v) { return __bfloat162float(v); }
DEVI bf16 f2bf(float v) { return __float2bfloat16(v); }

DEVI unsigned short bfbits(float x) {
    bf16 h = __float2bfloat16(x);
    return *reinterpret_cast<unsigned short*>(&h);
}
DEVI unsigned int pack2(float x, float y) {
    return (unsigned int)bfbits(x) | ((unsigned int)bfbits(y) << 16);
}

// two packed bf16 (little-endian: low half = element 0) -> two floats
DEVI float2 unpack2(unsigned int u) {
    float2 r;
    r.x = __uint_as_float(u << 16);
    r.y = __uint_as_float(u & 0xffff0000u);
    return r;
}

// dot of 192 bf16 x 192 bf16, both from LDS, read as 96 packed uints.
// 4 independent accumulators for ILP.
DEVI float dot192(const unsigned int* __restrict__ a, const unsigned int* __restrict__ b) {
    float a0 = 0.f, a1 = 0.f, a2 = 0.f, a3 = 0.f;
#pragma unroll
    for (int c2 = 0; c2 < 96; c2 += 4) {
        float2 p0 = unpack2(a[c2]),     q0 = unpack2(b[c2]);
        float2 p1 = unpack2(a[c2 + 1]), q1 = unpack2(b[c2 + 1]);
        float2 p2 = unpack2(a[c2 + 2]), q2 = unpack2(b[c2 + 2]);
        float2 p3 = unpack2(a[c2 + 3]), q3 = unpack2(b[c2 + 3]);
        a0 = fmaf(p0.x, q0.x, a0); a0 = fmaf(p0.y, q0.y, a0);
        a1 = fmaf(p1.x, q1.x, a1); a1 = fmaf(p1.y, q1.y, a1);
        a2 = fmaf(p2.x, q2.x, a2); a2 = fmaf(p2.y, q2.y, a2);
        a3 = fmaf(p3.x, q3.x, a3); a3 = fmaf(p3.y, q3.y, a3);
    }
    return (a0 + a1) + (a2 + a3);
}

// ---------------------------------------------------------------------------
// Kernel 1: fused windowed attention, one block per (window, head).
// windows: wi = ((zw*16)+hw)*15 + ww ; tokens t = ((tz*6)+th)*12 + tw
// Writes attention output (pre-proj) rows (960*144, 192) bf16 to workspace.
// ---------------------------------------------------------------------------
__global__ __launch_bounds__(256) void attn_kernel(
    const float* __restrict__ x, const float* __restrict__ qkv_w,
    const float* __restrict__ qkv_b, const float* __restrict__ bias_table,
    bf16* __restrict__ attn_out)
{
    // LDS layout (byte offsets):
    //   xw   bf16 [144][194]  @0       (55872)   stride 97 words -> conflict-free
    //   wqkv bf16 [96][192]   @55872   (36864)   broadcast reads
    //   qf/kf/vf f32 [144][33]@92736/111744/130752 (19008 each)
    //   bq   f32 [96]         @149760
    //   S    f32 [144][145]   @0       (83520)   reuses xw+wqkv after phase 1
    __shared__ alignas(16) char sm[150144];
    bf16*  xw   = (bf16*)sm;
    bf16*  wqkv = (bf16*)(sm + 55872);
    float* qf   = (float*)(sm + 92736);
    float* kf   = (float*)(sm + 111744);
    float* vf   = (float*)(sm + 130752);
    float* bq   = (float*)(sm + 149760);
    float* S    = (float*)sm;

    const int tid  = threadIdx.x;
    const int wi   = blockIdx.x;      // 0..959
    const int head = blockIdx.y;      // 0..5
    const int ww_  = wi % 15;
    const int hw   = (wi / 15) % 16;
    const int zw   = wi / 240;
    const int wb   = zw * 16 + hw;    // bias window 0..63

    // Phase 0a: stage x window (zero-pad lat rows outside [0,91)), fp32 -> bf16
    for (int i = tid; i < 144 * 48; i += 256) {
        int t = i / 48, c4 = i - t * 48;     // c4 indexes a group of 4 floats
        int tz = t / 72, r_ = t - tz * 72;
        int th = r_ / 12, tw = r_ - th * 12;
        int z = zw * 2 + tz;
        int latp = hw * 6 + th;
        int lon = ww_ * 12 + tw;
        int lat = latp - 2;
        float4 v = make_float4(0.f, 0.f, 0.f, 0.f);
        if (lat >= 0 && lat < 91) {
            int gtok = (z * 91 + lat) * 180 + lon;
            v = *(const float4*)(x + (size_t)gtok * 192 + c4 * 4);
        }
        unsigned int* dst = (unsigned int*)(xw + t * 194 + c4 * 4);
        dst[0] = pack2(v.x, v.y);
        dst[1] = pack2(v.z, v.w);
    }
    // Phase 0b: stage this head's 96 qkv weight rows (q:0-31, k:32-63, v:64-95)
    for (int i = tid; i < 96 * 48; i += 256) {
        int r = i / 48, c4 = i - r * 48;
        int seg = r >> 5, rr = r & 31;
        int grow = seg * 192 + head * 32 + rr;
        float4 v = *(const float4*)(qkv_w + (size_t)grow * 192 + c4 * 4);
        unsigned int* dst = (unsigned int*)(wqkv + r * 192 + c4 * 4);
        dst[0] = pack2(v.x, v.y);
        dst[1] = pack2(v.z, v.w);
    }
    if (tid < 96) {
        int seg = tid >> 5;
        bq[tid] = qkv_b[seg * 192 + head * 32 + (tid & 31)];
    }
    __syncthreads();

    // Phase 1: qkv = xw @ Wqkv^T + b  (q scaled by 1/sqrt(32))
    const float scale = 0.17677669529663687f;
    for (int idx = tid; idx < 96 * 144; idx += 256) {
        int t = idx % 144, r = idx / 144;
        const unsigned int* xr = (const unsigned int*)(xw + t * 194);
        const unsigned int* wr = (const unsigned int*)(wqkv + r * 192);
        float sum = dot192(xr, wr) + bq[r];
        if (r < 32)       qf[t * 33 + r]      = sum * scale;
        else if (r < 64)  kf[t * 33 + r - 32] = sum;
        else              vf[t * 33 + r - 64] = sum;
    }
    __syncthreads();

    // Phase 2: S[n][m] = q[n].k[m] + earth bias (S overwrites xw/wqkv region)
    for (int idx = tid; idx < 144 * 144; idx += 256) {
        int n = idx / 144, m = idx - n * 144;
        const float* qn = qf + n * 33;
        const float* km = kf + m * 33;
        float a0 = 0.f, a1 = 0.f, a2 = 0.f, a3 = 0.f;
#pragma unroll
        for (int d = 0; d < 32; d += 4) {
            a0 = fmaf(qn[d],     km[d],     a0);
            a1 = fmaf(qn[d + 1], km[d + 1], a1);
            a2 = fmaf(qn[d + 2], km[d + 2], a2);
            a3 = fmaf(qn[d + 3], km[d + 3], a3);
        }
        int tzn = n / 72, thn = (n / 12) % 6, twn = n % 12;
        int tzm = m / 72, thm = (m / 12) % 6, twm = m % 12;
        int bidx = (tzn + 2 * tzm) * 828 + (thn + 6 * thm) * 23 + (twn - twm + 11);
        float bias = bias_table[(size_t)(bidx * 64 + wb) * 6 + head];
        S[n * 145 + m] = (a0 + a1) + (a2 + a3) + bias;
    }
    __syncthreads();

    // Phase 3: row softmax (one thread per row)
    if (tid < 144) {
        float* row = S + tid * 145;
        float mx = -1e30f;
        for (int j = 0; j < 144; ++j) mx = fmaxf(mx, row[j]);
        float s = 0.f;
        for (int j = 0; j < 144; ++j) { float e = __expf(row[j] - mx); row[j] = e; s += e; }
        float inv = 1.f / s;
        for (int j = 0; j < 144; ++j) row[j] *= inv;
    }
    __syncthreads();

    // Phase 4: out = S @ v -> attn_out[(wi*144+n)*192 + head*32 + d]
    for (int idx = tid; idx < 144 * 32; idx += 256) {
        int n = idx >> 5, d = idx & 31;
        const float* Sn = S + n * 145;
        float a0 = 0.f, a1 = 0.f, a2 = 0.f, a3 = 0.f;
#pragma unroll
        for (int m = 0; m < 144; m += 4) {
            a0 = fmaf(Sn[m],     vf[m * 33 + d],       a0);
            a1 = fmaf(Sn[m + 1], vf[(m + 1) * 33 + d], a1);
            a2 = fmaf(Sn[m + 2], vf[(m + 2) * 33 + d], a2);
            a3 = fmaf(Sn[m + 3], vf[(m + 3) * 33 + d], a3);
        }
        attn_out[(size_t)(wi * 144 + n) * 192 + (head << 5) + d] =
            f2bf((a0 + a1) + (a2 + a3));
    }
}

// ---------------------------------------------------------------------------
// Kernel 2: proj + window-reverse/crop + LN1 + residual -> x1 (bf16 ws)
// 32 tokens per block.
// ---------------------------------------------------------------------------
__global__ __launch_bounds__(256) void proj_ln_kernel(
    const bf16* __restrict__ attn, const float* __restrict__ proj_w,
    const float* __restrict__ proj_b, const float* __restrict__ xin,
    const float* __restrict__ n1w, const float* __restrict__ n1b,
    bf16* __restrict__ x1out)
{
    __shared__ alignas(16) char sm[111744];
    bf16*  pw = (bf16*)sm;             // [192][194] padded
    bf16*  aw = (bf16*)(sm + 74496);   // [32][192]
    float* p  = (float*)(sm + 86784);  // [32][193]
    float* mu = (float*)(sm + 111488); // [32]
    float* rs = (float*)(sm + 111616); // [32]

    const int tid = threadIdx.x;
    const int l0  = blockIdx.x * 32;

    for (int i = tid; i < 192 * 48; i += 256) {
        int r = i / 48, c4 = i - r * 48;
        float4 v = *(const float4*)(proj_w + (size_t)r * 192 + c4 * 4);
        unsigned int* dst = (unsigned int*)(pw + r * 194 + c4 * 4);
        dst[0] = pack2(v.x, v.y);
        dst[1] = pack2(v.z, v.w);
    }
    for (int i = tid; i < 32 * 24; i += 256) {
        int tl = i / 24, c4 = i - tl * 24;
        int l = l0 + tl;
        int z = l / 16380, rem = l - z * 16380;
        int lat = rem / 180, lon = rem - lat * 180;
        int latp = lat + 2;
        int zw = z >> 1, tz = z & 1;
        int hw = latp / 6, th = latp - hw * 6;
        int wwn = lon / 12, tw = lon - wwn * 12;
        int wi = (zw * 16 + hw) * 15 + wwn;
        int t  = (tz * 6 + th) * 12 + tw;
        uint4 v = *(const uint4*)(attn + (size_t)(wi * 144 + t) * 192 + c4 * 8);
        *(uint4*)(aw + tl * 192 + c4 * 8) = v;
    }
    __syncthreads();

    for (int idx = tid; idx < 32 * 192; idx += 256) {
        int tl = idx / 192, c = idx - tl * 192;
        const unsigned int* ar = (const unsigned int*)(aw + tl * 192);
        const unsigned int* wr = (const unsigned int*)(pw + c * 194);
        p[tl * 193 + c] = dot192(ar, wr) + proj_b[c];
    }
    __syncthreads();

    if (tid < 32) {
        const float* pr = p + tid * 193;
        float s = 0.f;
        for (int j = 0; j < 192; ++j) s += pr[j];
        float m = s * (1.f / 192.f);
        float v = 0.f;
        for (int j = 0; j < 192; ++j) { float d = pr[j] - m; v = fmaf(d, d, v); }
        mu[tid] = m;
        rs[tid] = rsqrtf(v * (1.f / 192.f) + 1e-5f);
    }
    __syncthreads();

    for (int idx = tid; idx < 32 * 96; idx += 256) {
        int tl = idx / 96, c = (idx - tl * 96) * 2;
        int l = l0 + tl;
        float v0 = (p[tl * 193 + c]     - mu[tl]) * rs[tl] * n1w[c]     + n1b[c]
                 + xin[(size_t)l * 192 + c];
        float v1 = (p[tl * 193 + c + 1] - mu[tl]) * rs[tl] * n1w[c + 1] + n1b[c + 1]
                 + xin[(size_t)l * 192 + c + 1];
        *(unsigned int*)(x1out + (size_t)l * 192 + c) = pack2(v0, v1);
    }
}

// ---------------------------------------------------------------------------
// Kernel 3: fused MLP (gelu exact) + LN2 + residual -> out (fp32). 16 tok/blk.
// ---------------------------------------------------------------------------
__global__ __launch_bounds__(256) void mlp_kernel(
    const bf16* __restrict__ x1, const float* __restrict__ w1,
    const float* __restrict__ b1, const float* __restrict__ w2,
    const float* __restrict__ b2, const float* __restrict__ n2w,
    const float* __restrict__ n2b, float* __restrict__ out)
{
    __shared__ alignas(16) char sm[117696];
    bf16*  wst = (bf16*)sm;             // [192][194] padded, reused for w1/w2 chunks
    bf16*  x1t = (bf16*)(sm + 74496);   // [16][192]
    bf16*  h1  = (bf16*)(sm + 80640);   // [16][768]
    float* mo  = (float*)(sm + 105216); // [16][193]
    float* mu  = (float*)(sm + 117568); // [16]
    float* rs  = (float*)(sm + 117632); // [16]

    const int tid = threadIdx.x;
    const int l0  = blockIdx.x * 16;

    for (int i = tid; i < 16 * 24; i += 256) {
        int tl = i / 24, c4 = i - tl * 24;
        uint4 v = *(const uint4*)(x1 + (size_t)(l0 + tl) * 192 + c4 * 8);
        *(uint4*)(x1t + tl * 192 + c4 * 8) = v;
    }

    // gemm1: h1 = gelu(x1 @ w1^T + b1), in 4 chunks of 192 w1-rows
    for (int rc = 0; rc < 4; ++rc) {
        __syncthreads();
        for (int i = tid; i < 192 * 48; i += 256) {
            int r = i / 48, c4 = i - r * 48;
            float4 v = *(const float4*)(w1 + (size_t)(rc * 192 + r) * 192 + c4 * 4);
            unsigned int* dst = (unsigned int*)(wst + r * 194 + c4 * 4);
            dst[0] = pack2(v.x, v.y);
            dst[1] = pack2(v.z, v.w);
        }
        __syncthreads();
        for (int idx = tid; idx < 16 * 192; idx += 256) {
            int tl = idx / 192, h = idx - tl * 192;
            const unsigned int* xr = (const unsigned int*)(x1t + tl * 192);
            const unsigned int* wr = (const unsigned int*)(wst + h * 194);
            float acc = dot192(xr, wr) + b1[rc * 192 + h];
            float g = 0.5f * acc * (1.f + erff(acc * 0.70710678118654752f));
            h1[tl * 768 + rc * 192 + h] = f2bf(g);
        }
    }

    // gemm2: mlp_out = h1 @ w2^T + b2, K tiled in 4 chunks of 192
    float acc2[12];
#pragma unroll
    for (int k = 0; k < 12; ++k) {
        int idx = tid + k * 256;
        acc2[k] = b2[idx % 192];
    }
    for (int jc = 0; jc < 4; ++jc) {
        __syncthreads();
        for (int i = tid; i < 192 * 48; i += 256) {
            int r = i / 48, c4 = i - r * 48;
            float4 v = *(const float4*)(w2 + (size_t)r * 768 + jc * 192 + c4 * 4);
            unsigned int* dst = (unsigned int*)(wst + r * 194 + c4 * 4);
            dst[0] = pack2(v.x, v.y);
            dst[1] = pack2(v.z, v.w);
        }
        __syncthreads();
#pragma unroll
        for (int k = 0; k < 12; ++k) {
            int idx = tid + k * 256;
            int tl = idx / 192, c = idx - tl * 192;
            const unsigned int* hr = (const unsigned int*)(h1 + tl * 768 + jc * 192);
            const unsigned int* wr = (const unsigned int*)(wst + c * 194);
            acc2[k] += dot192(hr, wr);
        }
    }
#pragma unroll
    for (int k = 0; k < 12; ++k) {
        int idx = tid + k * 256;
        int tl = idx / 192, c = idx - tl * 192;
        mo[tl * 193 + c] = acc2[k];
    }
    __syncthreads();

    if (tid < 16) {
        const float* pr = mo + tid * 193;
        float s = 0.f;
        for (int j = 0; j < 192; ++j) s += pr[j];
        float m = s * (1.f / 192.f);
        float v = 0.f;
        for (int j = 0; j < 192; ++j) { float d = pr[j] - m; v = fmaf(d, d, v); }
        mu[tid] = m;
        rs[tid] = rsqrtf(v * (1.f / 192.f) + 1e-5f);
    }
    __syncthreads();

    for (int idx = tid; idx < 16 * 96; idx += 256) {
        int tl = idx / 96, c = (idx - tl * 96) * 2;
        float v0 = (mo[tl * 193 + c]     - mu[tl]) * rs[tl] * n2w[c]     + n2b[c]
                 + bf2f(x1t[tl * 192 + c]);
        float v1 = (mo[tl * 193 + c + 1] - mu[tl]) * rs[tl] * n2w[c + 1] + n2b[c + 1]
                 + bf2f(x1t[tl * 192 + c + 1]);
        *(float2*)(out + (size_t)(l0 + tl) * 192 + c) = make_float2(v0, v1);
    }
}

// ---------------------------------------------------------------------------
extern "C" void kernel_launch(void* const* d_in, const int* in_sizes, int n_in,
                              void* d_out, int out_size, void* d_ws, size_t ws_size,
                              hipStream_t stream) {
    (void)in_sizes; (void)n_in; (void)out_size; (void)ws_size;
    const float* x          = (const float*)d_in[0];
    const float* qkv_w      = (const float*)d_in[1];
    const float* qkv_b      = (const float*)d_in[2];
    const float* proj_w     = (const float*)d_in[3];
    const float* proj_b     = (const float*)d_in[4];
    const float* bias_table = (const float*)d_in[5];
    const float* n1w        = (const float*)d_in[6];
    const float* n1b        = (const float*)d_in[7];
    const float* n2w        = (const float*)d_in[8];
    const float* n2b        = (const float*)d_in[9];
    const float* w1         = (const float*)d_in[10];
    const float* b1         = (const float*)d_in[11];
    const float* w2         = (const float*)d_in[12];
    const float* b2         = (const float*)d_in[13];
    float* out = (float*)d_out;

    // workspace: attn rows (960*144,192) bf16 = 53,084,160 B, then x1 (131040,192) bf16
    bf16* attn_ws = (bf16*)d_ws;
    bf16* x1_ws   = (bf16*)((char*)d_ws + 53084160);

    attn_kernel<<<dim3(960, 6), 256, 0, stream>>>(x, qkv_w, qkv_b, bias_table, attn_ws);
    proj_ln_kernel<<<4095, 256, 0, stream>>>(attn_ws, proj_w, proj_b, x, n1w, n1b, x1_ws);
    mlp_kernel<<<8190, 256, 0, stream>>>(x1_ws, w1, b1, w2, b2, n2w, n2b, out);
}

// Round 4
// 4713.292 us; speedup vs baseline: 2.1472x; 2.1472x over previous
//
#include <hip/hip_runtime.h>
#include <hip/hip_bf16.h>

typedef __hip_bfloat16 bf16;
#define DEVI __device__ __forceinline__

typedef __bf16 bf16x8 __attribute__((ext_vector_type(8)));
typedef float  f32x4  __attribute__((ext_vector_type(4)));

DEVI float bf2f(bf16 v) { return __bfloat162float(v); }
DEVI bf16 f2bf(float v) { return __float2bfloat16(v); }

DEVI unsigned short bfbits(float x) {
    bf16 h = __float2bfloat16(x);
    return *reinterpret_cast<unsigned short*>(&h);
}
DEVI unsigned int pack2(float x, float y) {
    return (unsigned int)bfbits(x) | ((unsigned int)bfbits(y) << 16);
}

DEVI float2 unpack2(unsigned int u) {
    float2 r;
    r.x = __uint_as_float(u << 16);
    r.y = __uint_as_float(u & 0xffff0000u);
    return r;
}

DEVI float dot192(const unsigned int* __restrict__ a, const unsigned int* __restrict__ b) {
    float a0 = 0.f, a1 = 0.f, a2 = 0.f, a3 = 0.f;
#pragma unroll
    for (int c2 = 0; c2 < 96; c2 += 4) {
        float2 p0 = unpack2(a[c2]),     q0 = unpack2(b[c2]);
        float2 p1 = unpack2(a[c2 + 1]), q1 = unpack2(b[c2 + 1]);
        float2 p2 = unpack2(a[c2 + 2]), q2 = unpack2(b[c2 + 2]);
        float2 p3 = unpack2(a[c2 + 3]), q3 = unpack2(b[c2 + 3]);
        a0 = fmaf(p0.x, q0.x, a0); a0 = fmaf(p0.y, q0.y, a0);
        a1 = fmaf(p1.x, q1.x, a1); a1 = fmaf(p1.y, q1.y, a1);
        a2 = fmaf(p2.x, q2.x, a2); a2 = fmaf(p2.y, q2.y, a2);
        a3 = fmaf(p3.x, q3.x, a3); a3 = fmaf(p3.y, q3.y, a3);
    }
    return (a0 + a1) + (a2 + a3);
}

// ---------------------------------------------------------------------------
// Kernel 1: fused windowed attention (unchanged from R2)
// ---------------------------------------------------------------------------
__global__ __launch_bounds__(256) void attn_kernel(
    const float* __restrict__ x, const float* __restrict__ qkv_w,
    const float* __restrict__ qkv_b, const float* __restrict__ bias_table,
    bf16* __restrict__ attn_out)
{
    __shared__ alignas(16) char sm[150144];
    bf16*  xw   = (bf16*)sm;
    bf16*  wqkv = (bf16*)(sm + 55872);
    float* qf   = (float*)(sm + 92736);
    float* kf   = (float*)(sm + 111744);
    float* vf   = (float*)(sm + 130752);
    float* bq   = (float*)(sm + 149760);
    float* S    = (float*)sm;

    const int tid  = threadIdx.x;
    const int wi   = blockIdx.x;
    const int head = blockIdx.y;
    const int ww_  = wi % 15;
    const int hw   = (wi / 15) % 16;
    const int zw   = wi / 240;
    const int wb   = zw * 16 + hw;

    for (int i = tid; i < 144 * 48; i += 256) {
        int t = i / 48, c4 = i - t * 48;
        int tz = t / 72, r_ = t - tz * 72;
        int th = r_ / 12, tw = r_ - th * 12;
        int z = zw * 2 + tz;
        int latp = hw * 6 + th;
        int lon = ww_ * 12 + tw;
        int lat = latp - 2;
        float4 v = make_float4(0.f, 0.f, 0.f, 0.f);
        if (lat >= 0 && lat < 91) {
            int gtok = (z * 91 + lat) * 180 + lon;
            v = *(const float4*)(x + (size_t)gtok * 192 + c4 * 4);
        }
        unsigned int* dst = (unsigned int*)(xw + t * 194 + c4 * 4);
        dst[0] = pack2(v.x, v.y);
        dst[1] = pack2(v.z, v.w);
    }
    for (int i = tid; i < 96 * 48; i += 256) {
        int r = i / 48, c4 = i - r * 48;
        int seg = r >> 5, rr = r & 31;
        int grow = seg * 192 + head * 32 + rr;
        float4 v = *(const float4*)(qkv_w + (size_t)grow * 192 + c4 * 4);
        unsigned int* dst = (unsigned int*)(wqkv + r * 192 + c4 * 4);
        dst[0] = pack2(v.x, v.y);
        dst[1] = pack2(v.z, v.w);
    }
    if (tid < 96) {
        int seg = tid >> 5;
        bq[tid] = qkv_b[seg * 192 + head * 32 + (tid & 31)];
    }
    __syncthreads();

    const float scale = 0.17677669529663687f;
    for (int idx = tid; idx < 96 * 144; idx += 256) {
        int t = idx % 144, r = idx / 144;
        const unsigned int* xr = (const unsigned int*)(xw + t * 194);
        const unsigned int* wr = (const unsigned int*)(wqkv + r * 192);
        float sum = dot192(xr, wr) + bq[r];
        if (r < 32)       qf[t * 33 + r]      = sum * scale;
        else if (r < 64)  kf[t * 33 + r - 32] = sum;
        else              vf[t * 33 + r - 64] = sum;
    }
    __syncthreads();

    for (int idx = tid; idx < 144 * 144; idx += 256) {
        int n = idx / 144, m = idx - n * 144;
        const float* qn = qf + n * 33;
        const float* km = kf + m * 33;
        float a0 = 0.f, a1 = 0.f, a2 = 0.f, a3 = 0.f;
#pragma unroll
        for (int d = 0; d < 32; d += 4) {
            a0 = fmaf(qn[d],     km[d],     a0);
            a1 = fmaf(qn[d + 1], km[d + 1], a1);
            a2 = fmaf(qn[d + 2], km[d + 2], a2);
            a3 = fmaf(qn[d + 3], km[d + 3], a3);
        }
        int tzn = n / 72, thn = (n / 12) % 6, twn = n % 12;
        int tzm = m / 72, thm = (m / 12) % 6, twm = m % 12;
        int bidx = (tzn + 2 * tzm) * 828 + (thn + 6 * thm) * 23 + (twn - twm + 11);
        float bias = bias_table[(size_t)(bidx * 64 + wb) * 6 + head];
        S[n * 145 + m] = (a0 + a1) + (a2 + a3) + bias;
    }
    __syncthreads();

    if (tid < 144) {
        float* row = S + tid * 145;
        float mx = -1e30f;
        for (int j = 0; j < 144; ++j) mx = fmaxf(mx, row[j]);
        float s = 0.f;
        for (int j = 0; j < 144; ++j) { float e = __expf(row[j] - mx); row[j] = e; s += e; }
        float inv = 1.f / s;
        for (int j = 0; j < 144; ++j) row[j] *= inv;
    }
    __syncthreads();

    for (int idx = tid; idx < 144 * 32; idx += 256) {
        int n = idx >> 5, d = idx & 31;
        const float* Sn = S + n * 145;
        float a0 = 0.f, a1 = 0.f, a2 = 0.f, a3 = 0.f;
#pragma unroll
        for (int m = 0; m < 144; m += 4) {
            a0 = fmaf(Sn[m],     vf[m * 33 + d],       a0);
            a1 = fmaf(Sn[m + 1], vf[(m + 1) * 33 + d], a1);
            a2 = fmaf(Sn[m + 2], vf[(m + 2) * 33 + d], a2);
            a3 = fmaf(Sn[m + 3], vf[(m + 3) * 33 + d], a3);
        }
        attn_out[(size_t)(wi * 144 + n) * 192 + (head << 5) + d] =
            f2bf((a0 + a1) + (a2 + a3));
    }
}

// ---------------------------------------------------------------------------
// Kernel 2: proj + window-reverse/crop + LN1 + residual -> x1 (unchanged)
// ---------------------------------------------------------------------------
__global__ __launch_bounds__(256) void proj_ln_kernel(
    const bf16* __restrict__ attn, const float* __restrict__ proj_w,
    const float* __restrict__ proj_b, const float* __restrict__ xin,
    const float* __restrict__ n1w, const float* __restrict__ n1b,
    bf16* __restrict__ x1out)
{
    __shared__ alignas(16) char sm[111744];
    bf16*  pw = (bf16*)sm;
    bf16*  aw = (bf16*)(sm + 74496);
    float* p  = (float*)(sm + 86784);
    float* mu = (float*)(sm + 111488);
    float* rs = (float*)(sm + 111616);

    const int tid = threadIdx.x;
    const int l0  = blockIdx.x * 32;

    for (int i = tid; i < 192 * 48; i += 256) {
        int r = i / 48, c4 = i - r * 48;
        float4 v = *(const float4*)(proj_w + (size_t)r * 192 + c4 * 4);
        unsigned int* dst = (unsigned int*)(pw + r * 194 + c4 * 4);
        dst[0] = pack2(v.x, v.y);
        dst[1] = pack2(v.z, v.w);
    }
    for (int i = tid; i < 32 * 24; i += 256) {
        int tl = i / 24, c4 = i - tl * 24;
        int l = l0 + tl;
        int z = l / 16380, rem = l - z * 16380;
        int lat = rem / 180, lon = rem - lat * 180;
        int latp = lat + 2;
        int zw = z >> 1, tz = z & 1;
        int hw = latp / 6, th = latp - hw * 6;
        int wwn = lon / 12, tw = lon - wwn * 12;
        int wi = (zw * 16 + hw) * 15 + wwn;
        int t  = (tz * 6 + th) * 12 + tw;
        uint4 v = *(const uint4*)(attn + (size_t)(wi * 144 + t) * 192 + c4 * 8);
        *(uint4*)(aw + tl * 192 + c4 * 8) = v;
    }
    __syncthreads();

    for (int idx = tid; idx < 32 * 192; idx += 256) {
        int tl = idx / 192, c = idx - tl * 192;
        const unsigned int* ar = (const unsigned int*)(aw + tl * 192);
        const unsigned int* wr = (const unsigned int*)(pw + c * 194);
        p[tl * 193 + c] = dot192(ar, wr) + proj_b[c];
    }
    __syncthreads();

    if (tid < 32) {
        const float* pr = p + tid * 193;
        float s = 0.f;
        for (int j = 0; j < 192; ++j) s += pr[j];
        float m = s * (1.f / 192.f);
        float v = 0.f;
        for (int j = 0; j < 192; ++j) { float d = pr[j] - m; v = fmaf(d, d, v); }
        mu[tid] = m;
        rs[tid] = rsqrtf(v * (1.f / 192.f) + 1e-5f);
    }
    __syncthreads();

    for (int idx = tid; idx < 32 * 96; idx += 256) {
        int tl = idx / 96, c = (idx - tl * 96) * 2;
        int l = l0 + tl;
        float v0 = (p[tl * 193 + c]     - mu[tl]) * rs[tl] * n1w[c]     + n1b[c]
                 + xin[(size_t)l * 192 + c];
        float v1 = (p[tl * 193 + c + 1] - mu[tl]) * rs[tl] * n1w[c + 1] + n1b[c + 1]
                 + xin[(size_t)l * 192 + c + 1];
        *(unsigned int*)(x1out + (size_t)l * 192 + c) = pack2(v0, v1);
    }
}

// ---------------------------------------------------------------------------
// Prep: convert w1 (768x192) and w2 (192x768) fp32 -> bf16 into workspace.
// ---------------------------------------------------------------------------
__global__ __launch_bounds__(256) void prep_weights(
    const float* __restrict__ w1, const float* __restrict__ w2,
    unsigned int* __restrict__ w1b, unsigned int* __restrict__ w2b)
{
    int i = blockIdx.x * 256 + threadIdx.x;   // pair index, 147456 total
    if (i < 73728) {
        w1b[i] = pack2(w1[2 * i], w1[2 * i + 1]);
    } else {
        int j = i - 73728;
        w2b[j] = pack2(w2[2 * j], w2[2 * j + 1]);
    }
}

// ---------------------------------------------------------------------------
// Kernel 3 (MFMA): fused MLP + LN2 + residual. 64 tokens/block, 4 waves.
// ---------------------------------------------------------------------------
__global__ __launch_bounds__(256, 2) void mlp_mfma_kernel(
    const bf16* __restrict__ x1, const bf16* __restrict__ w1b,
    const float* __restrict__ b1, const bf16* __restrict__ w2b,
    const float* __restrict__ b2, const float* __restrict__ n2w,
    const float* __restrict__ n2b, float* __restrict__ out)
{
    __shared__ alignas(16) char sm[53760];
    bf16*  Xs     = (bf16*)sm;               // [64][200] x1 tile
    bf16*  Hs     = (bf16*)(sm + 25600);     // [64][200] hidden chunk
    float* wsum   = (float*)(sm + 51200);    // [64][4]
    float* wsq    = (float*)(sm + 52224);    // [64][4]
    float* mean_s = (float*)(sm + 53248);    // [64]
    float* rstd_s = (float*)(sm + 53504);    // [64]

    const int tid  = threadIdx.x;
    const int wave = tid >> 6;
    const int lane = tid & 63;
    const int quad = lane >> 4;
    const int l15  = lane & 15;
    const long tok0 = (long)blockIdx.x * 64;
    const int colw = wave * 48;

    // stage X tile: 24 uint4 chunks (of 8 bf16) per 192-elem row  [R3 bug: was 12]
    for (int i = tid; i < 64 * 24; i += 256) {
        int r = i / 24, c8 = i - r * 24;
        uint4 v = make_uint4(0u, 0u, 0u, 0u);
        if (tok0 + r < 131040)
            v = *(const uint4*)(x1 + (tok0 + r) * 192 + (size_t)c8 * 8);
        *(uint4*)(Xs + r * 200 + c8 * 8) = v;
    }
    __syncthreads();

    // register-cache X A-fragments: af[mt][ks]
    bf16x8 af[4][6];
#pragma unroll
    for (int mt = 0; mt < 4; ++mt)
#pragma unroll
        for (int ks = 0; ks < 6; ++ks)
            af[mt][ks] = *(const bf16x8*)(Xs + (mt * 16 + l15) * 200 + ks * 32 + quad * 8);

    f32x4 o[3][4];
#pragma unroll
    for (int nt = 0; nt < 3; ++nt)
#pragma unroll
        for (int mt = 0; mt < 4; ++mt)
            o[nt][mt] = (f32x4){0.f, 0.f, 0.f, 0.f};

    for (int nc = 0; nc < 4; ++nc) {
        f32x4 g[3][4];
#pragma unroll
        for (int nt = 0; nt < 3; ++nt)
#pragma unroll
            for (int mt = 0; mt < 4; ++mt)
                g[nt][mt] = (f32x4){0.f, 0.f, 0.f, 0.f};
        const int h0 = nc * 192 + colw;
#pragma unroll
        for (int ks = 0; ks < 6; ++ks) {
            bf16x8 bfr[3];
#pragma unroll
            for (int nt = 0; nt < 3; ++nt)
                bfr[nt] = *(const bf16x8*)(w1b + (size_t)(h0 + nt * 16 + l15) * 192 + ks * 32 + quad * 8);
#pragma unroll
            for (int nt = 0; nt < 3; ++nt)
#pragma unroll
                for (int mt = 0; mt < 4; ++mt)
                    g[nt][mt] = __builtin_amdgcn_mfma_f32_16x16x32_bf16(
                        af[mt][ks], bfr[nt], g[nt][mt], 0, 0, 0);
        }
        __syncthreads();

#pragma unroll
        for (int nt = 0; nt < 3; ++nt) {
            float bb = b1[h0 + nt * 16 + l15];
            int hcol = colw + nt * 16 + l15;
#pragma unroll
            for (int mt = 0; mt < 4; ++mt) {
#pragma unroll
                for (int r = 0; r < 4; ++r) {
                    float v = g[nt][mt][r] + bb;
                    float u = v * (0.7978845608028654f + 0.035677408136300125f * v * v);
                    float e = __expf(2.f * u);
                    float t = 1.f - 2.f / (e + 1.f);
                    float gl = 0.5f * v * (1.f + t);
                    Hs[(mt * 16 + quad * 4 + r) * 200 + hcol] = f2bf(gl);
                }
            }
        }
        __syncthreads();

#pragma unroll
        for (int ks = 0; ks < 6; ++ks) {
            bf16x8 hf[4];
#pragma unroll
            for (int mt = 0; mt < 4; ++mt)
                hf[mt] = *(const bf16x8*)(Hs + (mt * 16 + l15) * 200 + ks * 32 + quad * 8);
            bf16x8 wf[3];
#pragma unroll
            for (int nt = 0; nt < 3; ++nt)
                wf[nt] = *(const bf16x8*)(w2b + (size_t)(colw + nt * 16 + l15) * 768 + nc * 192 + ks * 32 + quad * 8);
#pragma unroll
            for (int nt = 0; nt < 3; ++nt)
#pragma unroll
                for (int mt = 0; mt < 4; ++mt)
                    o[nt][mt] = __builtin_amdgcn_mfma_f32_16x16x32_bf16(
                        hf[mt], wf[nt], o[nt][mt], 0, 0, 0);
        }
    }

    // ---- epilogue ----
    float b2v[3], gw[3], gb[3];
#pragma unroll
    for (int nt = 0; nt < 3; ++nt) {
        int c = colw + nt * 16 + l15;
        b2v[nt] = b2[c];
        gw[nt] = n2w[c];
        gb[nt] = n2b[c];
    }
#pragma unroll
    for (int nt = 0; nt < 3; ++nt)
#pragma unroll
        for (int mt = 0; mt < 4; ++mt)
#pragma unroll
            for (int r = 0; r < 4; ++r)
                o[nt][mt][r] += b2v[nt];

#pragma unroll
    for (int mt = 0; mt < 4; ++mt) {
#pragma unroll
        for (int r = 0; r < 4; ++r) {
            float p = o[0][mt][r] + o[1][mt][r] + o[2][mt][r];
            float q = o[0][mt][r] * o[0][mt][r] + o[1][mt][r] * o[1][mt][r]
                    + o[2][mt][r] * o[2][mt][r];
#pragma unroll
            for (int m_ = 1; m_ < 16; m_ <<= 1) {
                p += __shfl_xor(p, m_, 64);
                q += __shfl_xor(q, m_, 64);
            }
            if (l15 == 0) {
                int row = mt * 16 + quad * 4 + r;
                wsum[row * 4 + wave] = p;
                wsq [row * 4 + wave] = q;
            }
        }
    }
    __syncthreads();
    if (tid < 64) {
        float s  = wsum[tid * 4] + wsum[tid * 4 + 1] + wsum[tid * 4 + 2] + wsum[tid * 4 + 3];
        float ss = wsq [tid * 4] + wsq [tid * 4 + 1] + wsq [tid * 4 + 2] + wsq [tid * 4 + 3];
        float m = s * (1.f / 192.f);
        float var = ss * (1.f / 192.f) - m * m;
        mean_s[tid] = m;
        rstd_s[tid] = rsqrtf(fmaxf(var, 0.f) + 1e-5f);
    }
    __syncthreads();

#pragma unroll
    for (int mt = 0; mt < 4; ++mt) {
#pragma unroll
        for (int r = 0; r < 4; ++r) {
            int row = mt * 16 + quad * 4 + r;
            long tok = tok0 + row;
            if (tok < 131040) {
                float m = mean_s[row], rsd = rstd_s[row];
#pragma unroll
                for (int nt = 0; nt < 3; ++nt) {
                    int c = colw + nt * 16 + l15;
                    float val = (o[nt][mt][r] - m) * rsd * gw[nt] + gb[nt]
                              + bf2f(Xs[row * 200 + c]);
                    out[tok * 192 + c] = val;
                }
            }
        }
    }
}

// ---------------------------------------------------------------------------
extern "C" void kernel_launch(void* const* d_in, const int* in_sizes, int n_in,
                              void* d_out, int out_size, void* d_ws, size_t ws_size,
                              hipStream_t stream) {
    (void)in_sizes; (void)n_in; (void)out_size; (void)ws_size;
    const float* x          = (const float*)d_in[0];
    const float* qkv_w      = (const float*)d_in[1];
    const float* qkv_b      = (const float*)d_in[2];
    const float* proj_w     = (const float*)d_in[3];
    const float* proj_b     = (const float*)d_in[4];
    const float* bias_table = (const float*)d_in[5];
    const float* n1w        = (const float*)d_in[6];
    const float* n1b        = (const float*)d_in[7];
    const float* n2w        = (const float*)d_in[8];
    const float* n2b        = (const float*)d_in[9];
    const float* w1         = (const float*)d_in[10];
    const float* b1         = (const float*)d_in[11];
    const float* w2         = (const float*)d_in[12];
    const float* b2         = (const float*)d_in[13];
    float* out = (float*)d_out;

    bf16* attn_ws = (bf16*)d_ws;
    bf16* x1_ws   = (bf16*)((char*)d_ws + 53084160);
    bf16* w1b     = (bf16*)d_ws;
    bf16* w2b     = (bf16*)((char*)d_ws + 294912);

    attn_kernel<<<dim3(960, 6), 256, 0, stream>>>(x, qkv_w, qkv_b, bias_table, attn_ws);
    proj_ln_kernel<<<4095, 256, 0, stream>>>(attn_ws, proj_w, proj_b, x, n1w, n1b, x1_ws);
    prep_weights<<<576, 256, 0, stream>>>(w1, w2, (unsigned int*)w1b, (unsigned int*)w2b);
    mlp_mfma_kernel<<<2048, 256, 0, stream>>>(x1_ws, w1b, b1, w2b, b2, n2w, n2b, out);
}

// Round 5
// 1396.541 us; speedup vs baseline: 7.2469x; 3.3750x over previous
//
#include <hip/hip_runtime.h>
#include <hip/hip_bf16.h>

typedef __hip_bfloat16 bf16;
#define DEVI __device__ __forceinline__

typedef __bf16 bf16x8 __attribute__((ext_vector_type(8)));
typedef __bf16 bf16x4 __attribute__((ext_vector_type(4)));
typedef float  f32x4  __attribute__((ext_vector_type(4)));

DEVI float bf2f(bf16 v) { return __bfloat162float(v); }
DEVI bf16 f2bf(float v) { return __float2bfloat16(v); }

DEVI unsigned short bfbits(float x) {
    bf16 h = __float2bfloat16(x);
    return *reinterpret_cast<unsigned short*>(&h);
}
DEVI unsigned int pack2(float x, float y) {
    return (unsigned int)bfbits(x) | ((unsigned int)bfbits(y) << 16);
}
DEVI float2 unpack2(unsigned int u) {
    float2 r;
    r.x = __uint_as_float(u << 16);
    r.y = __uint_as_float(u & 0xffff0000u);
    return r;
}
DEVI bf16x8 pack8(float4 lo, float4 hi) {
    union { unsigned int u[4]; bf16x8 v; } z;
    z.u[0] = pack2(lo.x, lo.y); z.u[1] = pack2(lo.z, lo.w);
    z.u[2] = pack2(hi.x, hi.y); z.u[3] = pack2(hi.z, hi.w);
    return z.v;
}
// LDS bf16x8 load from an 8-byte-aligned (not 16) address: two b64 halves
DEVI bf16x8 ld8h(const bf16* p) {
    bf16x4 lo = *(const bf16x4*)p;
    bf16x4 hi = *(const bf16x4*)(p + 4);
    return __builtin_shufflevector(lo, hi, 0, 1, 2, 3, 4, 5, 6, 7);
}

DEVI float dot192(const unsigned int* __restrict__ a, const unsigned int* __restrict__ b) {
    float a0 = 0.f, a1 = 0.f, a2 = 0.f, a3 = 0.f;
#pragma unroll
    for (int c2 = 0; c2 < 96; c2 += 4) {
        float2 p0 = unpack2(a[c2]),     q0 = unpack2(b[c2]);
        float2 p1 = unpack2(a[c2 + 1]), q1 = unpack2(b[c2 + 1]);
        float2 p2 = unpack2(a[c2 + 2]), q2 = unpack2(b[c2 + 2]);
        float2 p3 = unpack2(a[c2 + 3]), q3 = unpack2(b[c2 + 3]);
        a0 = fmaf(p0.x, q0.x, a0); a0 = fmaf(p0.y, q0.y, a0);
        a1 = fmaf(p1.x, q1.x, a1); a1 = fmaf(p1.y, q1.y, a1);
        a2 = fmaf(p2.x, q2.x, a2); a2 = fmaf(p2.y, q2.y, a2);
        a3 = fmaf(p3.x, q3.x, a3); a3 = fmaf(p3.y, q3.y, a3);
    }
    return (a0 + a1) + (a2 + a3);
}

// ---------------------------------------------------------------------------
// Prep A: reorder qkv weights per head into [h][96][192] bf16, fold 1/sqrt(32)
// into the q rows and q bias. qkv_bb fp32 [576] in [h][96] order.
// ---------------------------------------------------------------------------
__global__ __launch_bounds__(256) void prep_attn_w(
    const float* __restrict__ qkv_w, const float* __restrict__ qkv_b,
    bf16* __restrict__ qkv_wb, float* __restrict__ qkv_bb)
{
    const float scale = 0.17677669529663687f;
    int idx = blockIdx.x * 256 + threadIdx.x;
    if (idx < 110592) {
        int c = idx % 192, d = idx / 192;
        int h = d / 96, q2 = d - h * 96, seg = q2 >> 5, rr = q2 & 31;
        float v = qkv_w[(size_t)(seg * 192 + h * 32 + rr) * 192 + c];
        if (seg == 0) v *= scale;
        qkv_wb[idx] = f2bf(v);
    }
    if (idx < 576) {
        int h = idx / 96, q2 = idx - h * 96, seg = q2 >> 5, rr = q2 & 31;
        float b = qkv_b[seg * 192 + h * 32 + rr];
        if (seg == 0) b *= scale;
        qkv_bb[idx] = b;
    }
}

// ---------------------------------------------------------------------------
// Prep B: materialize earth bias tiles biasT[wb][h][n][m] bf16 (64*6*144*144)
// ---------------------------------------------------------------------------
__global__ __launch_bounds__(256) void prep_bias(
    const float* __restrict__ bias_table, bf16* __restrict__ biasT)
{
    int idx = blockIdx.x * 256 + threadIdx.x;
    if (idx >= 7962624) return;
    int m = idx % 144;
    int n = (idx / 144) % 144;
    int r2 = idx / 20736;
    int h = r2 % 6, wb = r2 / 6;
    int tzn = n / 72, thn = (n / 12) % 6, twn = n % 12;
    int tzm = m / 72, thm = (m / 12) % 6, twm = m % 12;
    int bidx = (tzn + 2 * tzm) * 828 + (thn + 6 * thm) * 23 + (twn - twm + 11);
    biasT[idx] = f2bf(bias_table[(size_t)(bidx * 64 + wb) * 6 + h]);
}

// ---------------------------------------------------------------------------
// Kernel 1 (MFMA): windowed attention, one block per (window, head), 4 waves.
// M-tiles (9) split {0,4,8},{1,5},{2,6},{3,7} across waves.
// ---------------------------------------------------------------------------
__global__ __launch_bounds__(256, 2) void attn_mfma_kernel(
    const float* __restrict__ x, const bf16* __restrict__ qkv_wb,
    const float* __restrict__ qkv_bb, const bf16* __restrict__ biasT,
    bf16* __restrict__ attn_out)
{
    // LDS: Q [144][36] @0 (10368) | K [144][36] @10368 | VT [32][168] @20736
    //      P [144][168] @31488 (48384)  -> total 79872 B, 2 blocks/CU
    __shared__ alignas(16) char sm[79872];
    bf16* Qs  = (bf16*)sm;
    bf16* Ks  = (bf16*)(sm + 10368);
    bf16* VTs = (bf16*)(sm + 20736);
    bf16* Ps  = (bf16*)(sm + 31488);

    const int tid  = threadIdx.x;
    const int wave = tid >> 6;
    const int lane = tid & 63;
    const int quad = lane >> 4;
    const int l15  = lane & 15;
    const int wi   = blockIdx.x;
    const int head = blockIdx.y;
    const int ww_  = wi % 15;
    const int hw   = (wi / 15) % 16;
    const int zw   = wi / 240;
    const int wb   = zw * 16 + hw;

    // zero VT pad cols [144,168)
    for (int i = tid; i < 32 * 24; i += 256) {
        int d = i / 24, c = i - d * 24;
        VTs[d * 168 + 144 + c] = f2bf(0.f);
    }

    const int nmt = (wave == 0) ? 3 : 2;

    // ---- load A-fragments of x window straight from global (fp32 -> bf16) ----
    bf16x8 af[3][6];
#pragma unroll
    for (int i = 0; i < 3; ++i) {
        int mt = wave + 4 * i;
        if (mt < 9) {
            int t  = mt * 16 + l15;
            int tz = t / 72, rr = t - tz * 72;
            int th = rr / 12, tw = rr - th * 12;
            int lat = hw * 6 + th - 2;
            bool valid = (lat >= 0 && lat < 91);
            size_t base = ((size_t)((zw * 2 + tz) * 91 + (valid ? lat : 0)) * 180
                           + ww_ * 12 + tw) * 192;
#pragma unroll
            for (int ks = 0; ks < 6; ++ks) {
                float4 lo = make_float4(0.f, 0.f, 0.f, 0.f);
                float4 hi = make_float4(0.f, 0.f, 0.f, 0.f);
                if (valid) {
                    lo = *(const float4*)(x + base + ks * 32 + quad * 8);
                    hi = *(const float4*)(x + base + ks * 32 + quad * 8 + 4);
                }
                af[i][ks] = pack8(lo, hi);
            }
        }
    }

    // ---- QKV GEMM: 6 N-tiles (q0 q1 k0 k1 v0 v1) ----
    for (int nt = 0; nt < 6; ++nt) {
        const bf16* wrow = qkv_wb + (size_t)(head * 96 + nt * 16 + l15) * 192;
        bf16x8 bw[6];
#pragma unroll
        for (int ks = 0; ks < 6; ++ks)
            bw[ks] = *(const bf16x8*)(wrow + ks * 32 + quad * 8);
        float bias = qkv_bb[head * 96 + nt * 16 + l15];

        f32x4 acc[3];
#pragma unroll
        for (int i = 0; i < 3; ++i) acc[i] = (f32x4){0.f, 0.f, 0.f, 0.f};
#pragma unroll
        for (int ks = 0; ks < 6; ++ks)
#pragma unroll
            for (int i = 0; i < 3; ++i) {
                int mt = wave + 4 * i;
                if (mt < 9)
                    acc[i] = __builtin_amdgcn_mfma_f32_16x16x32_bf16(
                        af[i][ks], bw[ks], acc[i], 0, 0, 0);
            }
#pragma unroll
        for (int i = 0; i < 3; ++i) {
            int mt = wave + 4 * i;
            if (mt < 9) {
#pragma unroll
                for (int r = 0; r < 4; ++r) {
                    float v = acc[i][r] + bias;
                    int tok = mt * 16 + quad * 4 + r;
                    if (nt < 2)      Qs[tok * 36 + nt * 16 + l15] = f2bf(v);
                    else if (nt < 4) Ks[tok * 36 + (nt - 2) * 16 + l15] = f2bf(v);
                    else             VTs[((nt - 4) * 16 + l15) * 168 + tok] = f2bf(v);
                }
            }
        }
    }
    __syncthreads();

    // ---- S = Q K^T + bias ----
    bf16x8 qa[3];
#pragma unroll
    for (int i = 0; i < 3; ++i) {
        int mt = wave + 4 * i;
        if (mt < 9) qa[i] = ld8h(Qs + (mt * 16 + l15) * 36 + quad * 8);
    }
    f32x4 sa[3][9];
    for (int nt = 0; nt < 9; ++nt) {
        bf16x8 kb = ld8h(Ks + (nt * 16 + l15) * 36 + quad * 8);
#pragma unroll
        for (int i = 0; i < 3; ++i) {
            int mt = wave + 4 * i;
            sa[i][nt] = (f32x4){0.f, 0.f, 0.f, 0.f};
            if (mt < 9)
                sa[i][nt] = __builtin_amdgcn_mfma_f32_16x16x32_bf16(
                    qa[i], kb, sa[i][nt], 0, 0, 0);
        }
    }
    const bf16* bt = biasT + (size_t)(wb * 6 + head) * 20736;
#pragma unroll
    for (int i = 0; i < 3; ++i) {
        int mt = wave + 4 * i;
        if (mt < 9) {
#pragma unroll
            for (int nt = 0; nt < 9; ++nt)
#pragma unroll
                for (int r = 0; r < 4; ++r) {
                    int row = mt * 16 + quad * 4 + r;
                    sa[i][nt][r] += bf2f(bt[row * 144 + nt * 16 + l15]);
                }
        }
    }

    // ---- softmax (in-register, rows in quad) -> P (bf16 LDS, pad zeroed) ----
#pragma unroll
    for (int i = 0; i < 3; ++i) {
        int mt = wave + 4 * i;
        if (mt < 9) {
#pragma unroll
            for (int r = 0; r < 4; ++r) {
                float mx = -1e30f;
#pragma unroll
                for (int nt = 0; nt < 9; ++nt) mx = fmaxf(mx, sa[i][nt][r]);
#pragma unroll
                for (int msk = 1; msk < 16; msk <<= 1)
                    mx = fmaxf(mx, __shfl_xor(mx, msk, 64));
                float s = 0.f;
#pragma unroll
                for (int nt = 0; nt < 9; ++nt) {
                    float e = __expf(sa[i][nt][r] - mx);
                    sa[i][nt][r] = e;
                    s += e;
                }
#pragma unroll
                for (int msk = 1; msk < 16; msk <<= 1)
                    s += __shfl_xor(s, msk, 64);
                float inv = 1.f / s;
                int row = mt * 16 + quad * 4 + r;
#pragma unroll
                for (int nt = 0; nt < 9; ++nt)
                    Ps[row * 168 + nt * 16 + l15] = f2bf(sa[i][nt][r] * inv);
                Ps[row * 168 + 144 + l15] = f2bf(0.f);
            }
        }
    }

    // ---- O = P V  (K padded to 160 with zeros) ----
    f32x4 oa[3][2];
#pragma unroll
    for (int i = 0; i < 3; ++i)
#pragma unroll
        for (int n2 = 0; n2 < 2; ++n2) oa[i][n2] = (f32x4){0.f, 0.f, 0.f, 0.f};
#pragma unroll
    for (int ks = 0; ks < 5; ++ks) {
        bf16x8 vb[2];
#pragma unroll
        for (int n2 = 0; n2 < 2; ++n2)
            vb[n2] = *(const bf16x8*)(VTs + (n2 * 16 + l15) * 168 + ks * 32 + quad * 8);
#pragma unroll
        for (int i = 0; i < 3; ++i) {
            int mt = wave + 4 * i;
            if (mt < 9) {
                bf16x8 pa = *(const bf16x8*)(Ps + (mt * 16 + l15) * 168 + ks * 32 + quad * 8);
#pragma unroll
                for (int n2 = 0; n2 < 2; ++n2)
                    oa[i][n2] = __builtin_amdgcn_mfma_f32_16x16x32_bf16(
                        pa, vb[n2], oa[i][n2], 0, 0, 0);
            }
        }
    }

    // ---- store attn_out (same layout as before) ----
#pragma unroll
    for (int i = 0; i < 3; ++i) {
        int mt = wave + 4 * i;
        if (mt < 9) {
#pragma unroll
            for (int n2 = 0; n2 < 2; ++n2)
#pragma unroll
                for (int r = 0; r < 4; ++r) {
                    int tok = mt * 16 + quad * 4 + r;
                    attn_out[(size_t)(wi * 144 + tok) * 192 + (head << 5) + n2 * 16 + l15]
                        = f2bf(oa[i][n2][r]);
                }
        }
    }
}

// ---------------------------------------------------------------------------
// Kernel 2: proj + window-reverse/crop + LN1 + residual -> x1 (unchanged)
// ---------------------------------------------------------------------------
__global__ __launch_bounds__(256) void proj_ln_kernel(
    const bf16* __restrict__ attn, const float* __restrict__ proj_w,
    const float* __restrict__ proj_b, const float* __restrict__ xin,
    const float* __restrict__ n1w, const float* __restrict__ n1b,
    bf16* __restrict__ x1out)
{
    __shared__ alignas(16) char sm[111744];
    bf16*  pw = (bf16*)sm;
    bf16*  aw = (bf16*)(sm + 74496);
    float* p  = (float*)(sm + 86784);
    float* mu = (float*)(sm + 111488);
    float* rs = (float*)(sm + 111616);

    const int tid = threadIdx.x;
    const int l0  = blockIdx.x * 32;

    for (int i = tid; i < 192 * 48; i += 256) {
        int r = i / 48, c4 = i - r * 48;
        float4 v = *(const float4*)(proj_w + (size_t)r * 192 + c4 * 4);
        unsigned int* dst = (unsigned int*)(pw + r * 194 + c4 * 4);
        dst[0] = pack2(v.x, v.y);
        dst[1] = pack2(v.z, v.w);
    }
    for (int i = tid; i < 32 * 24; i += 256) {
        int tl = i / 24, c4 = i - tl * 24;
        int l = l0 + tl;
        int z = l / 16380, rem = l - z * 16380;
        int lat = rem / 180, lon = rem - lat * 180;
        int latp = lat + 2;
        int zw = z >> 1, tz = z & 1;
        int hw = latp / 6, th = latp - hw * 6;
        int wwn = lon / 12, tw = lon - wwn * 12;
        int wi = (zw * 16 + hw) * 15 + wwn;
        int t  = (tz * 6 + th) * 12 + tw;
        uint4 v = *(const uint4*)(attn + (size_t)(wi * 144 + t) * 192 + c4 * 8);
        *(uint4*)(aw + tl * 192 + c4 * 8) = v;
    }
    __syncthreads();

    for (int idx = tid; idx < 32 * 192; idx += 256) {
        int tl = idx / 192, c = idx - tl * 192;
        const unsigned int* ar = (const unsigned int*)(aw + tl * 192);
        const unsigned int* wr = (const unsigned int*)(pw + c * 194);
        p[tl * 193 + c] = dot192(ar, wr) + proj_b[c];
    }
    __syncthreads();

    if (tid < 32) {
        const float* pr = p + tid * 193;
        float s = 0.f;
        for (int j = 0; j < 192; ++j) s += pr[j];
        float m = s * (1.f / 192.f);
        float v = 0.f;
        for (int j = 0; j < 192; ++j) { float d = pr[j] - m; v = fmaf(d, d, v); }
        mu[tid] = m;
        rs[tid] = rsqrtf(v * (1.f / 192.f) + 1e-5f);
    }
    __syncthreads();

    for (int idx = tid; idx < 32 * 96; idx += 256) {
        int tl = idx / 96, c = (idx - tl * 96) * 2;
        int l = l0 + tl;
        float v0 = (p[tl * 193 + c]     - mu[tl]) * rs[tl] * n1w[c]     + n1b[c]
                 + xin[(size_t)l * 192 + c];
        float v1 = (p[tl * 193 + c + 1] - mu[tl]) * rs[tl] * n1w[c + 1] + n1b[c + 1]
                 + xin[(size_t)l * 192 + c + 1];
        *(unsigned int*)(x1out + (size_t)l * 192 + c) = pack2(v0, v1);
    }
}

// ---------------------------------------------------------------------------
// Prep C: convert w1/w2 fp32 -> bf16 (unchanged)
// ---------------------------------------------------------------------------
__global__ __launch_bounds__(256) void prep_weights(
    const float* __restrict__ w1, const float* __restrict__ w2,
    unsigned int* __restrict__ w1b, unsigned int* __restrict__ w2b)
{
    int i = blockIdx.x * 256 + threadIdx.x;
    if (i < 73728) {
        w1b[i] = pack2(w1[2 * i], w1[2 * i + 1]);
    } else {
        int j = i - 73728;
        w2b[j] = pack2(w2[2 * j], w2[2 * j + 1]);
    }
}

// ---------------------------------------------------------------------------
// Kernel 3 (MFMA): fused MLP + LN2 + residual (unchanged from R4)
// ---------------------------------------------------------------------------
__global__ __launch_bounds__(256, 2) void mlp_mfma_kernel(
    const bf16* __restrict__ x1, const bf16* __restrict__ w1b,
    const float* __restrict__ b1, const bf16* __restrict__ w2b,
    const float* __restrict__ b2, const float* __restrict__ n2w,
    const float* __restrict__ n2b, float* __restrict__ out)
{
    __shared__ alignas(16) char sm[53760];
    bf16*  Xs     = (bf16*)sm;
    bf16*  Hs     = (bf16*)(sm + 25600);
    float* wsum   = (float*)(sm + 51200);
    float* wsq    = (float*)(sm + 52224);
    float* mean_s = (float*)(sm + 53248);
    float* rstd_s = (float*)(sm + 53504);

    const int tid  = threadIdx.x;
    const int wave = tid >> 6;
    const int lane = tid & 63;
    const int quad = lane >> 4;
    const int l15  = lane & 15;
    const long tok0 = (long)blockIdx.x * 64;
    const int colw = wave * 48;

    for (int i = tid; i < 64 * 24; i += 256) {
        int r = i / 24, c8 = i - r * 24;
        uint4 v = make_uint4(0u, 0u, 0u, 0u);
        if (tok0 + r < 131040)
            v = *(const uint4*)(x1 + (tok0 + r) * 192 + (size_t)c8 * 8);
        *(uint4*)(Xs + r * 200 + c8 * 8) = v;
    }
    __syncthreads();

    bf16x8 af[4][6];
#pragma unroll
    for (int mt = 0; mt < 4; ++mt)
#pragma unroll
        for (int ks = 0; ks < 6; ++ks)
            af[mt][ks] = *(const bf16x8*)(Xs + (mt * 16 + l15) * 200 + ks * 32 + quad * 8);

    f32x4 o[3][4];
#pragma unroll
    for (int nt = 0; nt < 3; ++nt)
#pragma unroll
        for (int mt = 0; mt < 4; ++mt)
            o[nt][mt] = (f32x4){0.f, 0.f, 0.f, 0.f};

    for (int nc = 0; nc < 4; ++nc) {
        f32x4 g[3][4];
#pragma unroll
        for (int nt = 0; nt < 3; ++nt)
#pragma unroll
            for (int mt = 0; mt < 4; ++mt)
                g[nt][mt] = (f32x4){0.f, 0.f, 0.f, 0.f};
        const int h0 = nc * 192 + colw;
#pragma unroll
        for (int ks = 0; ks < 6; ++ks) {
            bf16x8 bfr[3];
#pragma unroll
            for (int nt = 0; nt < 3; ++nt)
                bfr[nt] = *(const bf16x8*)(w1b + (size_t)(h0 + nt * 16 + l15) * 192 + ks * 32 + quad * 8);
#pragma unroll
            for (int nt = 0; nt < 3; ++nt)
#pragma unroll
                for (int mt = 0; mt < 4; ++mt)
                    g[nt][mt] = __builtin_amdgcn_mfma_f32_16x16x32_bf16(
                        af[mt][ks], bfr[nt], g[nt][mt], 0, 0, 0);
        }
        __syncthreads();

#pragma unroll
        for (int nt = 0; nt < 3; ++nt) {
            float bb = b1[h0 + nt * 16 + l15];
            int hcol = colw + nt * 16 + l15;
#pragma unroll
            for (int mt = 0; mt < 4; ++mt) {
#pragma unroll
                for (int r = 0; r < 4; ++r) {
                    float v = g[nt][mt][r] + bb;
                    float u = v * (0.7978845608028654f + 0.035677408136300125f * v * v);
                    float e = __expf(2.f * u);
                    float t = 1.f - 2.f / (e + 1.f);
                    float gl = 0.5f * v * (1.f + t);
                    Hs[(mt * 16 + quad * 4 + r) * 200 + hcol] = f2bf(gl);
                }
            }
        }
        __syncthreads();

#pragma unroll
        for (int ks = 0; ks < 6; ++ks) {
            bf16x8 hf[4];
#pragma unroll
            for (int mt = 0; mt < 4; ++mt)
                hf[mt] = *(const bf16x8*)(Hs + (mt * 16 + l15) * 200 + ks * 32 + quad * 8);
            bf16x8 wf[3];
#pragma unroll
            for (int nt = 0; nt < 3; ++nt)
                wf[nt] = *(const bf16x8*)(w2b + (size_t)(colw + nt * 16 + l15) * 768 + nc * 192 + ks * 32 + quad * 8);
#pragma unroll
            for (int nt = 0; nt < 3; ++nt)
#pragma unroll
                for (int mt = 0; mt < 4; ++mt)
                    o[nt][mt] = __builtin_amdgcn_mfma_f32_16x16x32_bf16(
                        hf[mt], wf[nt], o[nt][mt], 0, 0, 0);
        }
    }

    float b2v[3], gw[3], gb[3];
#pragma unroll
    for (int nt = 0; nt < 3; ++nt) {
        int c = colw + nt * 16 + l15;
        b2v[nt] = b2[c];
        gw[nt] = n2w[c];
        gb[nt] = n2b[c];
    }
#pragma unroll
    for (int nt = 0; nt < 3; ++nt)
#pragma unroll
        for (int mt = 0; mt < 4; ++mt)
#pragma unroll
            for (int r = 0; r < 4; ++r)
                o[nt][mt][r] += b2v[nt];

#pragma unroll
    for (int mt = 0; mt < 4; ++mt) {
#pragma unroll
        for (int r = 0; r < 4; ++r) {
            float p = o[0][mt][r] + o[1][mt][r] + o[2][mt][r];
            float q = o[0][mt][r] * o[0][mt][r] + o[1][mt][r] * o[1][mt][r]
                    + o[2][mt][r] * o[2][mt][r];
#pragma unroll
            for (int m_ = 1; m_ < 16; m_ <<= 1) {
                p += __shfl_xor(p, m_, 64);
                q += __shfl_xor(q, m_, 64);
            }
            if (l15 == 0) {
                int row = mt * 16 + quad * 4 + r;
                wsum[row * 4 + wave] = p;
                wsq [row * 4 + wave] = q;
            }
        }
    }
    __syncthreads();
    if (tid < 64) {
        float s  = wsum[tid * 4] + wsum[tid * 4 + 1] + wsum[tid * 4 + 2] + wsum[tid * 4 + 3];
        float ss = wsq [tid * 4] + wsq [tid * 4 + 1] + wsq [tid * 4 + 2] + wsq [tid * 4 + 3];
        float m = s * (1.f / 192.f);
        float var = ss * (1.f / 192.f) - m * m;
        mean_s[tid] = m;
        rstd_s[tid] = rsqrtf(fmaxf(var, 0.f) + 1e-5f);
    }
    __syncthreads();

#pragma unroll
    for (int mt = 0; mt < 4; ++mt) {
#pragma unroll
        for (int r = 0; r < 4; ++r) {
            int row = mt * 16 + quad * 4 + r;
            long tok = tok0 + row;
            if (tok < 131040) {
                float m = mean_s[row], rsd = rstd_s[row];
#pragma unroll
                for (int nt = 0; nt < 3; ++nt) {
                    int c = colw + nt * 16 + l15;
                    float val = (o[nt][mt][r] - m) * rsd * gw[nt] + gb[nt]
                              + bf2f(Xs[row * 200 + c]);
                    out[tok * 192 + c] = val;
                }
            }
        }
    }
}

// ---------------------------------------------------------------------------
extern "C" void kernel_launch(void* const* d_in, const int* in_sizes, int n_in,
                              void* d_out, int out_size, void* d_ws, size_t ws_size,
                              hipStream_t stream) {
    (void)in_sizes; (void)n_in; (void)out_size; (void)ws_size;
    const float* x          = (const float*)d_in[0];
    const float* qkv_w      = (const float*)d_in[1];
    const float* qkv_b      = (const float*)d_in[2];
    const float* proj_w     = (const float*)d_in[3];
    const float* proj_b     = (const float*)d_in[4];
    const float* bias_table = (const float*)d_in[5];
    const float* n1w        = (const float*)d_in[6];
    const float* n1b        = (const float*)d_in[7];
    const float* n2w        = (const float*)d_in[8];
    const float* n2b        = (const float*)d_in[9];
    const float* w1         = (const float*)d_in[10];
    const float* b1         = (const float*)d_in[11];
    const float* w2         = (const float*)d_in[12];
    const float* b2         = (const float*)d_in[13];
    float* out = (float*)d_out;

    // ws layout:
    //  [0, 53084160)            attn rows bf16 (dead after proj; start reused for w1b/w2b)
    //  [53084160, +50319360)    x1 bf16 (written by proj). BEFORE proj runs, this
    //                           region hosts attn prep data (read only by attn):
    //    qkv_wb @53084160 (221184 B) | qkv_bb @53305344 (2304 B) | biasT @53307648 (15925248 B)
    bf16*  attn_ws = (bf16*)d_ws;
    bf16*  x1_ws   = (bf16*)((char*)d_ws + 53084160);
    bf16*  w1b     = (bf16*)d_ws;
    bf16*  w2b     = (bf16*)((char*)d_ws + 294912);
    bf16*  qkv_wb  = (bf16*)((char*)d_ws + 53084160);
    float* qkv_bb  = (float*)((char*)d_ws + 53305344);
    bf16*  biasT   = (bf16*)((char*)d_ws + 53307648);

    prep_attn_w<<<432, 256, 0, stream>>>(qkv_w, qkv_b, qkv_wb, qkv_bb);
    prep_bias<<<31104, 256, 0, stream>>>(bias_table, biasT);
    attn_mfma_kernel<<<dim3(960, 6), 256, 0, stream>>>(x, qkv_wb, qkv_bb, biasT, attn_ws);
    proj_ln_kernel<<<4095, 256, 0, stream>>>(attn_ws, proj_w, proj_b, x, n1w, n1b, x1_ws);
    prep_weights<<<576, 256, 0, stream>>>(w1, w2, (unsigned int*)w1b, (unsigned int*)w2b);
    mlp_mfma_kernel<<<2048, 256, 0, stream>>>(x1_ws, w1b, b1, w2b, b2, n2w, n2b, out);
}